// Round 13
// baseline (206.412 us; speedup 1.0000x reference)
//
#include <hip/hip_runtime.h>
#include <hip/hip_bf16.h>
#include <stdint.h>

typedef __bf16 bf16;
typedef __attribute__((ext_vector_type(8))) __bf16 bf16x8;
typedef __attribute__((ext_vector_type(4))) float f32x4;

#define SEQ 2048
#define DIM 2048
#define NHEAD 32
#define HD 64
#define SCALE_L2E 0.18033688011112042f /* 0.125 * log2(e) */

__device__ __forceinline__ void gload16(void* lds, const void* g) {
  __builtin_amdgcn_global_load_lds(
      (const __attribute__((address_space(1))) unsigned int*)g,
      (__attribute__((address_space(3))) unsigned int*)lds, 16, 0, 0);
}

__device__ __forceinline__ f32x4 mfma16(bf16x8 a, bf16x8 b, f32x4 c) {
  return __builtin_amdgcn_mfma_f32_16x16x32_bf16(a, b, c, 0, 0, 0);
}

// ---------------- prep: z<4 = weight transpose+convert; z==4 = hs f32->bf16 --
__global__ __launch_bounds__(256) void prep(
    const float* __restrict__ hs, bf16* __restrict__ hsb,
    const float* __restrict__ w0, const float* __restrict__ w1,
    const float* __restrict__ w2, const float* __restrict__ w3,
    bf16* __restrict__ t0, bf16* __restrict__ t1,
    bf16* __restrict__ t2, bf16* __restrict__ t3) {
  int t = threadIdx.x;
  if (blockIdx.z == 4) {
    size_t i = ((size_t)(blockIdx.y * 32 + blockIdx.x) * 256 + t) * 16;
#pragma unroll
    for (int half = 0; half < 2; ++half) {
      f32x4 a = *(const f32x4*)(hs + i + half * 8);
      f32x4 b = *(const f32x4*)(hs + i + half * 8 + 4);
      bf16x8 o;
#pragma unroll
      for (int j = 0; j < 4; ++j) { o[j] = (bf16)a[j]; o[j + 4] = (bf16)b[j]; }
      *(bf16x8*)(hsb + i + half * 8) = o;
    }
    return;
  }
  const float* wsrc[4] = {w0, w1, w2, w3};
  bf16* wdst[4] = {t0, t1, t2, t3};
  const float* w = wsrc[blockIdx.z];
  bf16* wT = wdst[blockIdx.z];
  __shared__ alignas(16) bf16 tile[64][72];
  int n0 = blockIdx.x * 64, k0 = blockIdx.y * 64;
#pragma unroll
  for (int i = 0; i < 4; ++i) {
    int r = (t >> 4) + 16 * i;       // k offset
    int c = (t & 15) * 4;            // n offset
    f32x4 v = *(const f32x4*)(w + (size_t)(k0 + r) * DIM + n0 + c);
#pragma unroll
    for (int j = 0; j < 4; ++j) tile[r][c + j] = (bf16)v[j];
  }
  __syncthreads();
#pragma unroll
  for (int i = 0; i < 2; ++i) {
    int n = (t >> 3) + 32 * i;
    int kb = (t & 7) * 8;
    bf16x8 o;
#pragma unroll
    for (int j = 0; j < 8; ++j) o[j] = tile[kb + j][n];
    *(bf16x8*)(wT + (size_t)(n0 + n) * DIM + k0 + kb) = o;
  }
}

// ---------------- QKV GEMM: 256x256 tile, 8-phase counted-vmcnt schedule ----
// C = A @ Bt^T. 8 waves (2M x 4N), per-wave 128x64 out, acc[8][4].
// LDS slots [buf][khalf][256][32]: K-tile T lives in buf T&1; k-half s is
// read only in phases (T,2s),(T,2s+1) -> slot ring with one half-tile staged
// per phase: q0:A[T+1].k1  q1:B[T+1].k1  q2:A[T+2].k0  q3:B[T+2].k0.
// Each stage targets a slot whose last readers finished 2 barriers earlier
// (no latency assumptions). vmcnt(8) at odd phases = 4 half-tiles in flight.
// Raw s_barrier (no implicit vmcnt drain) keeps loads flying across phases.
// Swizzle: chunk ^= (row>>1)&3 within each 4-chunk half (pre-swizzled global
// source + linear LDS dest); per-16-lane bank spread <=2-way (free).
__global__ __launch_bounds__(512, 2) void gemm8p(
    const bf16* __restrict__ A,
    const bf16* __restrict__ B0, const bf16* __restrict__ B1, const bf16* __restrict__ B2,
    bf16* __restrict__ C0, bf16* __restrict__ C1, bf16* __restrict__ C2) {
  const int K = DIM, N = DIM;
  const bf16* Bt; bf16* C;
  if (blockIdx.z == 0)      { Bt = B0; C = C0; }
  else if (blockIdx.z == 1) { Bt = B1; C = C1; }
  else                      { Bt = B2; C = C2; }
  __shared__ alignas(16) bf16 As[2][2][256][32];   // [buf][khalf][row][k]
  __shared__ alignas(16) bf16 Bs[2][2][256][32];
  int o = blockIdx.y * 8 + blockIdx.x;             // 64 tiles per z
  int wgs = (o & 7) * 8 + (o >> 3);                // XCD swizzle, 64%8==0
  size_t mBase = (size_t)(wgs >> 3) * 256;
  size_t nBase = (size_t)(wgs & 7) * 256;
  int tid = threadIdx.x, lane = tid & 63, wid = tid >> 6;
  int wr = wid >> 2, wc = wid & 3;
  int lr = lane & 15, hi = lane >> 4;
  f32x4 acc[8][4] = {};

  // stage one half-tile (256 rows x 32 k): 2 gload16/thread, linear dest,
  // pre-swizzled source chunk.
  auto STG = [&](const bf16* src, bf16 (*dst)[2][256][32], int T, int s,
                 int b, size_t rbase) {
#pragma unroll
    for (int i = 0; i < 2; ++i) {
      int oo = i * 512 + tid;          // lane-slot 0..1023
      int row = oo >> 2;               // 0..255
      int cp = oo & 3;                 // physical chunk
      int cl = cp ^ ((row >> 1) & 3);  // logical chunk (involution)
      gload16(&dst[b][s][row][cp * 8],
              src + (rbase + row) * K + T * 64 + s * 32 + cl * 8);
    }
  };

  // prologue: A0.k0 B0.k0 A0.k1 B0.k1 A1.k0 B1.k0 (12 loads); wait oldest 4.
  STG(A, As, 0, 0, 0, mBase); STG(Bt, Bs, 0, 0, 0, nBase);
  STG(A, As, 0, 1, 0, mBase); STG(Bt, Bs, 0, 1, 0, nBase);
  STG(A, As, 1, 0, 1, mBase); STG(Bt, Bs, 1, 0, 1, nBase);
  asm volatile("s_waitcnt vmcnt(8)" ::: "memory");
  __builtin_amdgcn_s_barrier();

  bf16x8 bsr[4];
  for (int T = 0; T < 32; ++T) {
    int cur = T & 1;
#pragma unroll
    for (int q = 0; q < 4; ++q) {
      const int s = q >> 1, f = q & 1;
      // ds_read this phase's fragments
      bf16x8 ar[4];
#pragma unroll
      for (int mm = 0; mm < 4; ++mm) {
        int row = wr * 128 + (f * 4 + mm) * 16 + lr;
        int cp = hi ^ ((row >> 1) & 3);
        ar[mm] = *(const bf16x8*)&As[cur][s][row][cp * 8];
      }
      if (f == 0) {
#pragma unroll
        for (int n = 0; n < 4; ++n) {
          int row = wc * 64 + n * 16 + lr;
          int cp = hi ^ ((row >> 1) & 3);
          bsr[n] = *(const bf16x8*)&Bs[cur][s][row][cp * 8];
        }
      }
      // stage one half-tile (ring schedule)
      if (q == 0) { if (T + 1 < 32) STG(A,  As, T + 1, 1, cur ^ 1, mBase); }
      else if (q == 1) { if (T + 1 < 32) STG(Bt, Bs, T + 1, 1, cur ^ 1, nBase); }
      else if (q == 2) { if (T + 2 < 32) STG(A,  As, T + 2, 0, cur, mBase); }
      else             { if (T + 2 < 32) STG(Bt, Bs, T + 2, 0, cur, nBase); }
      __builtin_amdgcn_s_barrier();                    // BAR1
      asm volatile("s_waitcnt lgkmcnt(0)");
      __builtin_amdgcn_sched_barrier(0);
      __builtin_amdgcn_s_setprio(1);
#pragma unroll
      for (int mm = 0; mm < 4; ++mm)
#pragma unroll
        for (int n = 0; n < 4; ++n)
          acc[f * 4 + mm][n] = mfma16(ar[mm], bsr[n], acc[f * 4 + mm][n]);
      __builtin_amdgcn_s_setprio(0);
      if (q & 1) asm volatile("s_waitcnt vmcnt(8)" ::: "memory");
      __builtin_amdgcn_s_barrier();                    // BAR2
    }
  }
  // epilogue
#pragma unroll
  for (int m = 0; m < 8; ++m)
#pragma unroll
    for (int n = 0; n < 4; ++n)
#pragma unroll
      for (int j = 0; j < 4; ++j) {
        size_t row = mBase + wr * 128 + m * 16 + hi * 4 + j;
        size_t col = nBase + wc * 64 + n * 16 + lr;
        C[row * N + col] = (bf16)acc[m][n][j];
      }
}

// ---- out-projection: in-block split-K (8 waves = 2 K-groups), LDS reduce ----
__global__ __launch_bounds__(512) void gemm_out(
    const bf16* __restrict__ A, const bf16* __restrict__ Bt,
    float* __restrict__ Y) {
  const int K = DIM, N = DIM;
  __shared__ alignas(16) bf16 As[2][128][64];   // [group][row][k]
  __shared__ alignas(16) bf16 Bs[2][128][64];
  __shared__ alignas(16) float red[128][132];   // +4 pad: 2-way banks max
  int tid = threadIdx.x;
  int grp = tid >> 8;
  int gt = tid & 255;
  int lane = gt & 63, w = gt >> 6;
  int wr = w >> 1, wc = w & 1;
  size_t mBase = (size_t)blockIdx.y * 128, nBase = (size_t)blockIdx.x * 128;
  f32x4 acc[4][4] = {};
  int r0 = gt >> 3, sl = gt & 7;
  int lr = lane & 15, hi = lane >> 4, sw = lr & 7;
  int kbeg = grp * (K / 2);
  for (int kt = kbeg; kt < kbeg + K / 2; kt += 64) {
#pragma unroll
    for (int i = 0; i < 4; ++i) {
      int row = r0 + 32 * i;
      int kc = sl ^ (row & 7);
      gload16(&As[grp][row][sl * 8], A + (mBase + row) * K + kt + kc * 8);
      gload16(&Bs[grp][row][sl * 8], Bt + (nBase + row) * K + kt + kc * 8);
    }
    __syncthreads();
#pragma unroll
    for (int kk = 0; kk < 2; ++kk) {
      int cb = kk * 4 + hi;
      bf16x8 a[4], b[4];
#pragma unroll
      for (int m = 0; m < 4; ++m)
        a[m] = *(const bf16x8*)&As[grp][wr * 64 + m * 16 + lr][(cb ^ sw) * 8];
#pragma unroll
      for (int n = 0; n < 4; ++n)
        b[n] = *(const bf16x8*)&Bs[grp][wc * 64 + n * 16 + lr][(cb ^ sw) * 8];
#pragma unroll
      for (int m = 0; m < 4; ++m)
#pragma unroll
        for (int n = 0; n < 4; ++n)
          acc[m][n] = mfma16(a[m], b[n], acc[m][n]);
    }
    __syncthreads();
  }
  if (grp == 1) {
#pragma unroll
    for (int m = 0; m < 4; ++m)
#pragma unroll
      for (int n = 0; n < 4; ++n)
#pragma unroll
        for (int j = 0; j < 4; ++j)
          red[wr * 64 + m * 16 + hi * 4 + j][wc * 64 + n * 16 + lr] = acc[m][n][j];
  }
  __syncthreads();
  if (grp == 0) {
#pragma unroll
    for (int m = 0; m < 4; ++m)
#pragma unroll
      for (int n = 0; n < 4; ++n)
#pragma unroll
        for (int j = 0; j < 4; ++j) {
          int row = wr * 64 + m * 16 + hi * 4 + j;
          int col = wc * 64 + n * 16 + lr;
          Y[(mBase + row) * N + nBase + col] = acc[m][n][j] + red[row][col];
        }
  }
}

// ---- fused rope(q,k)+k-blend AND v-blend+transpose, one launch -------------
__global__ __launch_bounds__(256) void qkvprep(
    const bf16* __restrict__ qraw, const bf16* __restrict__ kraw,
    const bf16* __restrict__ vraw,
    const float* __restrict__ fc, const float* __restrict__ fs,
    const float* __restrict__ kcache, const float* __restrict__ kmask,
    const float* __restrict__ vcache, const float* __restrict__ vmask,
    float* __restrict__ kout, float* __restrict__ vout,
    bf16* __restrict__ qb, bf16* __restrict__ kb, bf16* __restrict__ vtb) {
  __shared__ alignas(16) bf16 tile[64][72];
  int bid = blockIdx.x;
  if (bid < SEQ) {
    int s = bid;
    int c0 = threadIdx.x * 8;
    int h = c0 >> 6, d0 = c0 & 63;
    float km = kmask[s], omk = 1.0f - km;
    size_t src = (size_t)s * DIM + c0;
    f32x4 cc = *(const f32x4*)(fc + s * 32 + (d0 >> 1));
    f32x4 ss = *(const f32x4*)(fs + s * 32 + (d0 >> 1));
    bf16x8 qv = *(const bf16x8*)(qraw + src);
    bf16x8 kv = *(const bf16x8*)(kraw + src);
    float kcf[8];
    *(f32x4*)(kcf) = *(const f32x4*)(kcache + src);
    *(f32x4*)(kcf + 4) = *(const f32x4*)(kcache + src + 4);
    bf16x8 qo, ko;
    float kof[8];
#pragma unroll
    for (int i = 0; i < 4; ++i) {
      float c = cc[i], sn = ss[i];
      float qr = (float)qv[2 * i], qi = (float)qv[2 * i + 1];
      qo[2 * i]     = (bf16)(qr * c - qi * sn);
      qo[2 * i + 1] = (bf16)(qr * sn + qi * c);
      float kr = (float)kv[2 * i], ki = (float)kv[2 * i + 1];
      float b0 = kcf[2 * i] * omk + (kr * c - ki * sn) * km;
      float b1 = kcf[2 * i + 1] * omk + (kr * sn + ki * c) * km;
      kof[2 * i] = b0; kof[2 * i + 1] = b1;
      ko[2 * i] = (bf16)b0; ko[2 * i + 1] = (bf16)b1;
    }
    *(f32x4*)(kout + src) = *(f32x4*)kof;
    *(f32x4*)(kout + src + 4) = *(f32x4*)(kof + 4);
    size_t dsth = ((size_t)h * SEQ + s) * HD + d0;
    *(bf16x8*)(qb + dsth) = qo;
    *(bf16x8*)(kb + dsth) = ko;
    return;
  }
  int vb = bid - SEQ;
  int h = vb >> 5;
  int s0 = (vb & 31) * 64;
  int t = threadIdx.x;
#pragma unroll
  for (int i = 0; i < 4; ++i) {
    int r = (t >> 4) + 16 * i;   // s offset
    int c = (t & 15) * 4;        // hd offset
    int s = s0 + r;
    float vm = vmask[s], om = 1.0f - vm;
    size_t src = (size_t)s * DIM + h * 64 + c;
    f32x4 vc = *(const f32x4*)(vcache + src);
    f32x4 o;
#pragma unroll
    for (int j = 0; j < 4; ++j) {
      float val = vc[j] * om + (float)vraw[src + j] * vm;
      o[j] = val;
      tile[r][c + j] = (bf16)val;
    }
    *(f32x4*)(vout + src) = o;
  }
  __syncthreads();
#pragma unroll
  for (int i = 0; i < 2; ++i) {
    int hd = (t >> 3) + 32 * i;
    int cb = (t & 7) * 8;
    bf16x8 o;
#pragma unroll
    for (int j = 0; j < 8; ++j) o[j] = tile[cb + j][hd];
    *(bf16x8*)(vtb + (size_t)h * HD * SEQ + (size_t)hd * SEQ + s0 + cb) = o;
  }
}

// ---------------- causal flash attention: 8-wave, 128-q-row tiles -----------
// (R12-measured structure, unchanged)
__global__ __launch_bounds__(512) void attn_fwd(
    const bf16* __restrict__ qb, const bf16* __restrict__ kb,
    const bf16* __restrict__ vtb, bf16* __restrict__ ob) {
  int orig = blockIdx.x;                 // 256 blocks, 256%8==0 -> bijective
  int wg = (orig & 7) * 32 + (orig >> 3);
  int h = wg >> 3;                       // 4 consecutive heads per XCD
  int qp = wg & 7;
  int qtA = qp, qtB = 15 - qp;           // q-tiles of 128 rows
  int ntA = qtA + 1;                     // KV tiles for segment A
  const int NT = 17;
  __shared__ alignas(16) bf16 Ks[2][128][64];
  __shared__ alignas(16) bf16 Vs[2][64][128];   // V^T tile: [hd][key]
  __shared__ alignas(16) bf16 Ps[8][16][128];   // per-wave P: [q][key]
  int tid = threadIdx.x, lane = tid & 63, w = tid >> 6;
  const bf16* qh = qb + (size_t)h * SEQ * HD;
  const bf16* kh = kb + (size_t)h * SEQ * HD;
  const bf16* vh = vtb + (size_t)h * HD * SEQ;
  int lr = lane & 15, hi = lane >> 4, sw = lr & 7;
  int qrowA = qtA * 128 + w * 16 + lr;
  int qrowB = qtB * 128 + w * 16 + lr;
  bf16x8 qfA[2], qfB[2];
#pragma unroll
  for (int kk = 0; kk < 2; ++kk) {
    qfA[kk] = *(const bf16x8*)(qh + (size_t)qrowA * HD + kk * 32 + hi * 8);
    qfB[kk] = *(const bf16x8*)(qh + (size_t)qrowB * HD + kk * 32 + hi * 8);
  }
  f32x4 otA[4] = {}, otB[4] = {};
  float mA = -3e38f, lA = 0.f, mB = -3e38f, lB = 0.f;
  char* PsW = (char*)&Ps[w][0][0];

  auto STAGE = [&](int kv0, int b) {
    int kr0 = tid >> 3, ksl = tid & 7;
#pragma unroll
    for (int i = 0; i < 2; ++i) {
      int row = kr0 + 64 * i;
      int kc = ksl ^ (row & 7);
      gload16(&Ks[b][row][ksl * 8], kh + (size_t)(kv0 + row) * HD + kc * 8);
    }
    int vr0 = tid >> 4, vsl = tid & 15;
#pragma unroll
    for (int i = 0; i < 2; ++i) {
      int row = vr0 + 32 * i;
      int vc = vsl ^ (row & 7);
      gload16(&Vs[b][row][vsl * 8], vh + (size_t)row * SEQ + kv0 + vc * 8);
    }
  };

  auto BODY = [&](int buf, int kv0, bf16x8 (&qf)[2], f32x4 (&ot)[4],
                  float& mrun, float& lrun, int qrow, bool last) {
    f32x4 st[8] = {};
    __builtin_amdgcn_s_setprio(1);
#pragma unroll
    for (int kk = 0; kk < 2; ++kk) {
      int cb = kk * 4 + hi;
#pragma unroll
      for (int n = 0; n < 8; ++n) {
        bf16x8 kf = *(const bf16x8*)&Ks[buf][n * 16 + lr][(cb ^ sw) * 8];
        st[n] = mfma16(kf, qf[kk], st[n]);
      }
    }
    __builtin_amdgcn_s_setprio(0);
    if (last) {
#pragma unroll
      for (int n = 0; n < 8; ++n)
#pragma unroll
        for (int j = 0; j < 4; ++j) {
          int key = kv0 + n * 16 + hi * 4 + j;
          st[n][j] = (key <= qrow) ? st[n][j] * SCALE_L2E : -1e30f;
        }
    } else {
#pragma unroll
      for (int n = 0; n < 8; ++n)
#pragma unroll
        for (int j = 0; j < 4; ++j) st[n][j] *= SCALE_L2E;
    }
    float tm[8];
#pragma unroll
    for (int n = 0; n < 8; ++n)
      tm[n] = fmaxf(fmaxf(st[n][0], st[n][1]), fmaxf(st[n][2], st[n][3]));
    float t01 = fmaxf(tm[0], tm[1]), t23 = fmaxf(tm[2], tm[3]);
    float t45 = fmaxf(tm[4], tm[5]), t67 = fmaxf(tm[6], tm[7]);
    float tmax = fmaxf(fmaxf(t01, t23), fmaxf(t45, t67));
    tmax = fmaxf(tmax, __shfl_xor(tmax, 16));
    tmax = fmaxf(tmax, __shfl_xor(tmax, 32));
    if (!__all(tmax <= mrun + 8.f)) {
      float mnew = fmaxf(mrun, tmax);
      float alpha = exp2f(mrun - mnew);
      mrun = mnew;
      lrun *= alpha;
#pragma unroll
      for (int nd = 0; nd < 4; ++nd)
#pragma unroll
        for (int j = 0; j < 4; ++j) ot[nd][j] *= alpha;
    }
    float ps[8];
#pragma unroll
    for (int n = 0; n < 8; ++n) {
      float p0 = exp2f(st[n][0] - mrun), p1 = exp2f(st[n][1] - mrun);
      float p2 = exp2f(st[n][2] - mrun), p3 = exp2f(st[n][3] - mrun);
      st[n][0] = p0; st[n][1] = p1; st[n][2] = p2; st[n][3] = p3;
      ps[n] = (p0 + p1) + (p2 + p3);
    }
    float psum = ((ps[0] + ps[1]) + (ps[2] + ps[3])) +
                 ((ps[4] + ps[5]) + (ps[6] + ps[7]));
    psum += __shfl_xor(psum, 16);
    psum += __shfl_xor(psum, 32);
    lrun += psum;
#pragma unroll
    for (int n = 0; n < 8; ++n) {
      union { bf16 b[4]; uint2 u; } pk;
#pragma unroll
      for (int j = 0; j < 4; ++j) pk.b[j] = (bf16)st[n][j];
      int keyc = n * 2 + (hi >> 1);
      *(uint2*)(PsW + lr * 256 + ((keyc ^ sw) * 16) + (hi & 1) * 8) = pk.u;
    }
    __builtin_amdgcn_s_setprio(1);
#pragma unroll
    for (int kk = 0; kk < 4; ++kk) {
      int cb = kk * 4 + hi;
      bf16x8 pf = *(const bf16x8*)(PsW + lr * 256 + ((cb ^ sw) * 16));
#pragma unroll
      for (int nd = 0; nd < 4; ++nd) {
        bf16x8 vf = *(const bf16x8*)&Vs[buf][nd * 16 + lr][(cb ^ sw) * 8];
        ot[nd] = mfma16(vf, pf, ot[nd]);
      }
    }
    __builtin_amdgcn_s_setprio(0);
  };

  auto STORE = [&](f32x4 (&ot)[4], float lrun, int qrow) {
    float rinv = 1.0f / lrun;
    bf16* orow = ob + ((size_t)h * SEQ + qrow) * HD;
#pragma unroll
    for (int nd = 0; nd < 4; ++nd) {
      union { bf16 b[4]; uint2 u; } o;
#pragma unroll
      for (int j = 0; j < 4; ++j) o.b[j] = (bf16)(ot[nd][j] * rinv);
      *(uint2*)(orow + nd * 16 + hi * 4) = o.u;
    }
  };

  STAGE(0, 0);
  int buf = 0;
  for (int t = 0; t < NT; ++t) {
    __syncthreads();
    if (t + 1 < NT) {
      int tn = t + 1;
      int kvn = (tn < ntA ? tn : tn - ntA) * 128;
      STAGE(kvn, buf ^ 1);
    }
    if (t < ntA) {
      int kv0 = t * 128;
      BODY(buf, kv0, qfA, otA, mA, lA, qrowA, t == ntA - 1);
      if (t == ntA - 1) STORE(otA, lA, qrowA);
    } else {
      int kv0 = (t - ntA) * 128;
      BODY(buf, kv0, qfB, otB, mB, lB, qrowB, t == NT - 1);
    }
    buf ^= 1;
  }
  STORE(otB, lB, qrowB);
}

extern "C" void kernel_launch(void* const* d_in, const int* in_sizes, int n_in,
                              void* d_out, int out_size, void* d_ws, size_t ws_size,
                              hipStream_t stream) {
  const float* hs     = (const float*)d_in[0];
  const float* fc     = (const float*)d_in[1];
  const float* fs     = (const float*)d_in[2];
  // d_in[3] = attention_mask (analytic causal; unused)
  const float* kcache = (const float*)d_in[4];
  const float* vcache = (const float*)d_in[5];
  const float* kmask  = (const float*)d_in[6];
  const float* vmask  = (const float*)d_in[7];
  const float* wq     = (const float*)d_in[8];
  const float* wk     = (const float*)d_in[9];
  const float* wv     = (const float*)d_in[10];
  const float* wo     = (const float*)d_in[11];

  float* y    = (float*)d_out;
  float* kout = y + (size_t)SEQ * DIM;
  float* vout = y + 2 * (size_t)SEQ * DIM;

  char* ws = (char*)d_ws;
  const size_t MB8 = (size_t)SEQ * DIM * sizeof(bf16);  // 8 MiB
  bf16* wqT  = (bf16*)(ws + 0 * MB8);
  bf16* wkT  = (bf16*)(ws + 1 * MB8);
  bf16* wvT  = (bf16*)(ws + 2 * MB8);
  bf16* woT  = (bf16*)(ws + 3 * MB8);
  bf16* hsb  = (bf16*)(ws + 4 * MB8);
  bf16* qraw = (bf16*)(ws + 5 * MB8);
  bf16* kraw = (bf16*)(ws + 6 * MB8);
  bf16* vraw = (bf16*)(ws + 7 * MB8);
  bf16* qb   = (bf16*)(ws + 8 * MB8);
  bf16* kb   = (bf16*)(ws + 9 * MB8);
  bf16* vtb  = (bf16*)(ws + 10 * MB8);
  bf16* ob   = hsb;  // hsb dead after QKV GEMM; reuse for attention output

  prep<<<dim3(32, 32, 5), dim3(256), 0, stream>>>(
      hs, hsb, wq, wk, wv, wo, wqT, wkT, wvT, woT);
  gemm8p<<<dim3(8, 8, 3), dim3(512), 0, stream>>>(
      hsb, wqT, wkT, wvT, qraw, kraw, vraw);
  qkvprep<<<dim3(SEQ + 1024), dim3(256), 0, stream>>>(
      qraw, kraw, vraw, fc, fs, kcache, kmask, vcache, vmask,
      kout, vout, qb, kb, vtb);
  attn_fwd<<<dim3(256), dim3(512), 0, stream>>>(qb, kb, vtb, ob);
  gemm_out<<<dim3(16, 16), dim3(512), 0, stream>>>(ob, woT, y);
}

// Round 14
// 187.405 us; speedup vs baseline: 1.1014x; 1.1014x over previous
//
#include <hip/hip_runtime.h>
#include <hip/hip_bf16.h>
#include <stdint.h>

typedef __bf16 bf16;
typedef __attribute__((ext_vector_type(8))) __bf16 bf16x8;
typedef __attribute__((ext_vector_type(4))) float f32x4;

#define SEQ 2048
#define DIM 2048
#define NHEAD 32
#define HD 64
#define SCALE_L2E 0.18033688011112042f /* 0.125 * log2(e) */

__device__ __forceinline__ void gload16(void* lds, const void* g) {
  __builtin_amdgcn_global_load_lds(
      (const __attribute__((address_space(1))) unsigned int*)g,
      (__attribute__((address_space(3))) unsigned int*)lds, 16, 0, 0);
}

__device__ __forceinline__ f32x4 mfma16(bf16x8 a, bf16x8 b, f32x4 c) {
  return __builtin_amdgcn_mfma_f32_16x16x32_bf16(a, b, c, 0, 0, 0);
}

// ---------------- prep: z<4 = weight transpose+convert; z==4 = hs f32->bf16 --
__global__ __launch_bounds__(256) void prep(
    const float* __restrict__ hs, bf16* __restrict__ hsb,
    const float* __restrict__ w0, const float* __restrict__ w1,
    const float* __restrict__ w2, const float* __restrict__ w3,
    bf16* __restrict__ t0, bf16* __restrict__ t1,
    bf16* __restrict__ t2, bf16* __restrict__ t3) {
  int t = threadIdx.x;
  if (blockIdx.z == 4) {
    size_t i = ((size_t)(blockIdx.y * 32 + blockIdx.x) * 256 + t) * 16;
#pragma unroll
    for (int half = 0; half < 2; ++half) {
      f32x4 a = *(const f32x4*)(hs + i + half * 8);
      f32x4 b = *(const f32x4*)(hs + i + half * 8 + 4);
      bf16x8 o;
#pragma unroll
      for (int j = 0; j < 4; ++j) { o[j] = (bf16)a[j]; o[j + 4] = (bf16)b[j]; }
      *(bf16x8*)(hsb + i + half * 8) = o;
    }
    return;
  }
  const float* wsrc[4] = {w0, w1, w2, w3};
  bf16* wdst[4] = {t0, t1, t2, t3};
  const float* w = wsrc[blockIdx.z];
  bf16* wT = wdst[blockIdx.z];
  __shared__ alignas(16) bf16 tile[64][72];
  int n0 = blockIdx.x * 64, k0 = blockIdx.y * 64;
#pragma unroll
  for (int i = 0; i < 4; ++i) {
    int r = (t >> 4) + 16 * i;       // k offset
    int c = (t & 15) * 4;            // n offset
    f32x4 v = *(const f32x4*)(w + (size_t)(k0 + r) * DIM + n0 + c);
#pragma unroll
    for (int j = 0; j < 4; ++j) tile[r][c + j] = (bf16)v[j];
  }
  __syncthreads();
#pragma unroll
  for (int i = 0; i < 2; ++i) {
    int n = (t >> 3) + 32 * i;
    int kb = (t & 7) * 8;
    bf16x8 o;
#pragma unroll
    for (int j = 0; j < 8; ++j) o[j] = tile[kb + j][n];
    *(bf16x8*)(wT + (size_t)(n0 + n) * DIM + k0 + kb) = o;
  }
}

// ---------------- 128x128 bf16 GEMM, C = A @ Bt^T  (A: MxK, Bt: NxK) --------
// R12-measured structure (64us QKV, 805 TF) — the m97-class ceiling.
template <typename OutT>
__global__ __launch_bounds__(256) void gemm128(
    const bf16* __restrict__ A,
    const bf16* __restrict__ B0, const bf16* __restrict__ B1, const bf16* __restrict__ B2,
    OutT* __restrict__ C0, OutT* __restrict__ C1, OutT* __restrict__ C2,
    int M, int N, int K) {
  const bf16* Bt; OutT* C;
  if (blockIdx.z == 0)      { Bt = B0; C = C0; }
  else if (blockIdx.z == 1) { Bt = B1; C = C1; }
  else                      { Bt = B2; C = C2; }
  __shared__ alignas(16) bf16 As[128][64];
  __shared__ alignas(16) bf16 Bs[128][64];
  int tid = threadIdx.x, lane = tid & 63, w = tid >> 6;
  int wr = w >> 1, wc = w & 1;
  size_t mBase = (size_t)blockIdx.y * 128, nBase = (size_t)blockIdx.x * 128;
  f32x4 acc[4][4] = {};
  int r0 = tid >> 3, sl = tid & 7;
  int lr = lane & 15, hi = lane >> 4, sw = lr & 7;
  for (int kt = 0; kt < K; kt += 64) {
#pragma unroll
    for (int i = 0; i < 4; ++i) {
      int row = r0 + 32 * i;
      int kc = sl ^ (row & 7);
      gload16(&As[row][sl * 8], A + (mBase + row) * K + kt + kc * 8);
      gload16(&Bs[row][sl * 8], Bt + (nBase + row) * K + kt + kc * 8);
    }
    __syncthreads();
#pragma unroll
    for (int kk = 0; kk < 2; ++kk) {
      int cb = kk * 4 + hi;
      bf16x8 a[4], b[4];
#pragma unroll
      for (int m = 0; m < 4; ++m)
        a[m] = *(const bf16x8*)&As[wr * 64 + m * 16 + lr][(cb ^ sw) * 8];
#pragma unroll
      for (int n = 0; n < 4; ++n)
        b[n] = *(const bf16x8*)&Bs[wc * 64 + n * 16 + lr][(cb ^ sw) * 8];
#pragma unroll
      for (int m = 0; m < 4; ++m)
#pragma unroll
        for (int n = 0; n < 4; ++n)
          acc[m][n] = mfma16(a[m], b[n], acc[m][n]);
    }
    __syncthreads();
  }
#pragma unroll
  for (int m = 0; m < 4; ++m)
#pragma unroll
    for (int n = 0; n < 4; ++n)
#pragma unroll
      for (int j = 0; j < 4; ++j) {
        size_t row = mBase + wr * 64 + m * 16 + hi * 4 + j;
        size_t col = nBase + wc * 64 + n * 16 + lr;
        C[row * N + col] = (OutT)acc[m][n][j];
      }
}

// ---- out-projection: in-block split-K (8 waves = 2 K-groups), LDS reduce ----
__global__ __launch_bounds__(512) void gemm_out(
    const bf16* __restrict__ A, const bf16* __restrict__ Bt,
    float* __restrict__ Y) {
  const int K = DIM, N = DIM;
  __shared__ alignas(16) bf16 As[2][128][64];   // [group][row][k]
  __shared__ alignas(16) bf16 Bs[2][128][64];
  __shared__ alignas(16) float red[128][132];   // +4 pad: 2-way banks max
  int tid = threadIdx.x;
  int grp = tid >> 8;
  int gt = tid & 255;
  int lane = gt & 63, w = gt >> 6;
  int wr = w >> 1, wc = w & 1;
  size_t mBase = (size_t)blockIdx.y * 128, nBase = (size_t)blockIdx.x * 128;
  f32x4 acc[4][4] = {};
  int r0 = gt >> 3, sl = gt & 7;
  int lr = lane & 15, hi = lane >> 4, sw = lr & 7;
  int kbeg = grp * (K / 2);
  for (int kt = kbeg; kt < kbeg + K / 2; kt += 64) {
#pragma unroll
    for (int i = 0; i < 4; ++i) {
      int row = r0 + 32 * i;
      int kc = sl ^ (row & 7);
      gload16(&As[grp][row][sl * 8], A + (mBase + row) * K + kt + kc * 8);
      gload16(&Bs[grp][row][sl * 8], Bt + (nBase + row) * K + kt + kc * 8);
    }
    __syncthreads();
#pragma unroll
    for (int kk = 0; kk < 2; ++kk) {
      int cb = kk * 4 + hi;
      bf16x8 a[4], b[4];
#pragma unroll
      for (int m = 0; m < 4; ++m)
        a[m] = *(const bf16x8*)&As[grp][wr * 64 + m * 16 + lr][(cb ^ sw) * 8];
#pragma unroll
      for (int n = 0; n < 4; ++n)
        b[n] = *(const bf16x8*)&Bs[grp][wc * 64 + n * 16 + lr][(cb ^ sw) * 8];
#pragma unroll
      for (int m = 0; m < 4; ++m)
#pragma unroll
        for (int n = 0; n < 4; ++n)
          acc[m][n] = mfma16(a[m], b[n], acc[m][n]);
    }
    __syncthreads();
  }
  if (grp == 1) {
#pragma unroll
    for (int m = 0; m < 4; ++m)
#pragma unroll
      for (int n = 0; n < 4; ++n)
#pragma unroll
        for (int j = 0; j < 4; ++j)
          red[wr * 64 + m * 16 + hi * 4 + j][wc * 64 + n * 16 + lr] = acc[m][n][j];
  }
  __syncthreads();
  if (grp == 0) {
#pragma unroll
    for (int m = 0; m < 4; ++m)
#pragma unroll
      for (int n = 0; n < 4; ++n)
#pragma unroll
        for (int j = 0; j < 4; ++j) {
          int row = wr * 64 + m * 16 + hi * 4 + j;
          int col = wc * 64 + n * 16 + lr;
          Y[(mBase + row) * N + nBase + col] = acc[m][n][j] + red[row][col];
        }
  }
}

// ---- fused rope(q,k)+k-blend AND v-blend+transpose, one launch -------------
__global__ __launch_bounds__(256) void qkvprep(
    const bf16* __restrict__ qraw, const bf16* __restrict__ kraw,
    const bf16* __restrict__ vraw,
    const float* __restrict__ fc, const float* __restrict__ fs,
    const float* __restrict__ kcache, const float* __restrict__ kmask,
    const float* __restrict__ vcache, const float* __restrict__ vmask,
    float* __restrict__ kout, float* __restrict__ vout,
    bf16* __restrict__ qb, bf16* __restrict__ kb, bf16* __restrict__ vtb) {
  __shared__ alignas(16) bf16 tile[64][72];
  int bid = blockIdx.x;
  if (bid < SEQ) {
    int s = bid;
    int c0 = threadIdx.x * 8;
    int h = c0 >> 6, d0 = c0 & 63;
    float km = kmask[s], omk = 1.0f - km;
    size_t src = (size_t)s * DIM + c0;
    f32x4 cc = *(const f32x4*)(fc + s * 32 + (d0 >> 1));
    f32x4 ss = *(const f32x4*)(fs + s * 32 + (d0 >> 1));
    bf16x8 qv = *(const bf16x8*)(qraw + src);
    bf16x8 kv = *(const bf16x8*)(kraw + src);
    float kcf[8];
    *(f32x4*)(kcf) = *(const f32x4*)(kcache + src);
    *(f32x4*)(kcf + 4) = *(const f32x4*)(kcache + src + 4);
    bf16x8 qo, ko;
    float kof[8];
#pragma unroll
    for (int i = 0; i < 4; ++i) {
      float c = cc[i], sn = ss[i];
      float qr = (float)qv[2 * i], qi = (float)qv[2 * i + 1];
      qo[2 * i]     = (bf16)(qr * c - qi * sn);
      qo[2 * i + 1] = (bf16)(qr * sn + qi * c);
      float kr = (float)kv[2 * i], ki = (float)kv[2 * i + 1];
      float b0 = kcf[2 * i] * omk + (kr * c - ki * sn) * km;
      float b1 = kcf[2 * i + 1] * omk + (kr * sn + ki * c) * km;
      kof[2 * i] = b0; kof[2 * i + 1] = b1;
      ko[2 * i] = (bf16)b0; ko[2 * i + 1] = (bf16)b1;
    }
    *(f32x4*)(kout + src) = *(f32x4*)kof;
    *(f32x4*)(kout + src + 4) = *(f32x4*)(kof + 4);
    size_t dsth = ((size_t)h * SEQ + s) * HD + d0;
    *(bf16x8*)(qb + dsth) = qo;
    *(bf16x8*)(kb + dsth) = ko;
    return;
  }
  int vb = bid - SEQ;
  int h = vb >> 5;
  int s0 = (vb & 31) * 64;
  int t = threadIdx.x;
#pragma unroll
  for (int i = 0; i < 4; ++i) {
    int r = (t >> 4) + 16 * i;   // s offset
    int c = (t & 15) * 4;        // hd offset
    int s = s0 + r;
    float vm = vmask[s], om = 1.0f - vm;
    size_t src = (size_t)s * DIM + h * 64 + c;
    f32x4 vc = *(const f32x4*)(vcache + src);
    f32x4 o;
#pragma unroll
    for (int j = 0; j < 4; ++j) {
      float val = vc[j] * om + (float)vraw[src + j] * vm;
      o[j] = val;
      tile[r][c + j] = (bf16)val;
    }
    *(f32x4*)(vout + src) = o;
  }
  __syncthreads();
#pragma unroll
  for (int i = 0; i < 2; ++i) {
    int hd = (t >> 3) + 32 * i;
    int cb = (t & 7) * 8;
    bf16x8 o;
#pragma unroll
    for (int j = 0; j < 8; ++j) o[j] = tile[cb + j][hd];
    *(bf16x8*)(vtb + (size_t)h * HD * SEQ + (size_t)hd * SEQ + s0 + cb) = o;
  }
}

// ---------------- causal flash attention: 8-wave, single-buffer, 2 blk/CU ---
// qb,kb: [NHEAD][SEQ][HD] bf16 ; vtb: [NHEAD][HD][SEQ] bf16
// ob: HEAD-MAJOR [NHEAD][SEQ][HD] bf16 (== swapaxes(0,1).reshape order, b=1)
// 256 blocks x 512 thr; block = q-tiles (qp, 15-qp) of 128 rows, flat 17 KV
// tiles (128 keys). SINGLE K/V buffer: LDS 64KB -> 2 blocks/CU (16 waves/CU);
// the staging latency of one block hides under the other block's compute
// (cross-block TLP replaces the double-buffer's intra-block prefetch).
__global__ __launch_bounds__(512) void attn_fwd(
    const bf16* __restrict__ qb, const bf16* __restrict__ kb,
    const bf16* __restrict__ vtb, bf16* __restrict__ ob) {
  int orig = blockIdx.x;                 // 256 blocks, 256%8==0 -> bijective
  int wg = (orig & 7) * 32 + (orig >> 3);
  int h = wg >> 3;                       // 4 consecutive heads per XCD
  int qp = wg & 7;
  int qtA = qp, qtB = 15 - qp;           // q-tiles of 128 rows
  int ntA = qtA + 1;                     // KV tiles for segment A
  const int NT = 17;
  __shared__ alignas(16) bf16 Ks[128][64];
  __shared__ alignas(16) bf16 Vs[64][128];   // V^T tile: [hd][key]
  __shared__ alignas(16) bf16 Ps[8][16][128];// per-wave P: [q][key]
  int tid = threadIdx.x, lane = tid & 63, w = tid >> 6;
  const bf16* qh = qb + (size_t)h * SEQ * HD;
  const bf16* kh = kb + (size_t)h * SEQ * HD;
  const bf16* vh = vtb + (size_t)h * HD * SEQ;
  int lr = lane & 15, hi = lane >> 4, sw = lr & 7;
  int qrowA = qtA * 128 + w * 16 + lr;
  int qrowB = qtB * 128 + w * 16 + lr;
  bf16x8 qfA[2], qfB[2];
#pragma unroll
  for (int kk = 0; kk < 2; ++kk) {
    qfA[kk] = *(const bf16x8*)(qh + (size_t)qrowA * HD + kk * 32 + hi * 8);
    qfB[kk] = *(const bf16x8*)(qh + (size_t)qrowB * HD + kk * 32 + hi * 8);
  }
  f32x4 otA[4] = {}, otB[4] = {};
  float mA = -3e38f, lA = 0.f, mB = -3e38f, lB = 0.f;
  char* PsW = (char*)&Ps[w][0][0];

  auto STAGE = [&](int kv0) {
    int kr0 = tid >> 3, ksl = tid & 7;
#pragma unroll
    for (int i = 0; i < 2; ++i) {
      int row = kr0 + 64 * i;
      int kc = ksl ^ (row & 7);
      gload16(&Ks[row][ksl * 8], kh + (size_t)(kv0 + row) * HD + kc * 8);
    }
    int vr0 = tid >> 4, vsl = tid & 15;
#pragma unroll
    for (int i = 0; i < 2; ++i) {
      int row = vr0 + 32 * i;
      int vc = vsl ^ (row & 7);
      gload16(&Vs[row][vsl * 8], vh + (size_t)row * SEQ + kv0 + vc * 8);
    }
  };

  auto BODY = [&](int kv0, bf16x8 (&qf)[2], f32x4 (&ot)[4],
                  float& mrun, float& lrun, int qrow, bool last) {
    f32x4 st[8] = {};
    __builtin_amdgcn_s_setprio(1);
#pragma unroll
    for (int kk = 0; kk < 2; ++kk) {
      int cb = kk * 4 + hi;
#pragma unroll
      for (int n = 0; n < 8; ++n) {
        bf16x8 kf = *(const bf16x8*)&Ks[n * 16 + lr][(cb ^ sw) * 8];
        st[n] = mfma16(kf, qf[kk], st[n]);
      }
    }
    __builtin_amdgcn_s_setprio(0);
    if (last) {
#pragma unroll
      for (int n = 0; n < 8; ++n)
#pragma unroll
        for (int j = 0; j < 4; ++j) {
          int key = kv0 + n * 16 + hi * 4 + j;
          st[n][j] = (key <= qrow) ? st[n][j] * SCALE_L2E : -1e30f;
        }
    } else {
#pragma unroll
      for (int n = 0; n < 8; ++n)
#pragma unroll
        for (int j = 0; j < 4; ++j) st[n][j] *= SCALE_L2E;
    }
    float tm[8];
#pragma unroll
    for (int n = 0; n < 8; ++n)
      tm[n] = fmaxf(fmaxf(st[n][0], st[n][1]), fmaxf(st[n][2], st[n][3]));
    float t01 = fmaxf(tm[0], tm[1]), t23 = fmaxf(tm[2], tm[3]);
    float t45 = fmaxf(tm[4], tm[5]), t67 = fmaxf(tm[6], tm[7]);
    float tmax = fmaxf(fmaxf(t01, t23), fmaxf(t45, t67));
    tmax = fmaxf(tmax, __shfl_xor(tmax, 16));
    tmax = fmaxf(tmax, __shfl_xor(tmax, 32));
    if (!__all(tmax <= mrun + 8.f)) {
      float mnew = fmaxf(mrun, tmax);
      float alpha = exp2f(mrun - mnew);
      mrun = mnew;
      lrun *= alpha;
#pragma unroll
      for (int nd = 0; nd < 4; ++nd)
#pragma unroll
        for (int j = 0; j < 4; ++j) ot[nd][j] *= alpha;
    }
    float ps[8];
#pragma unroll
    for (int n = 0; n < 8; ++n) {
      float p0 = exp2f(st[n][0] - mrun), p1 = exp2f(st[n][1] - mrun);
      float p2 = exp2f(st[n][2] - mrun), p3 = exp2f(st[n][3] - mrun);
      st[n][0] = p0; st[n][1] = p1; st[n][2] = p2; st[n][3] = p3;
      ps[n] = (p0 + p1) + (p2 + p3);
    }
    float psum = ((ps[0] + ps[1]) + (ps[2] + ps[3])) +
                 ((ps[4] + ps[5]) + (ps[6] + ps[7]));
    psum += __shfl_xor(psum, 16);
    psum += __shfl_xor(psum, 32);
    lrun += psum;
#pragma unroll
    for (int n = 0; n < 8; ++n) {
      union { bf16 b[4]; uint2 u; } pk;
#pragma unroll
      for (int j = 0; j < 4; ++j) pk.b[j] = (bf16)st[n][j];
      int keyc = n * 2 + (hi >> 1);
      *(uint2*)(PsW + lr * 256 + ((keyc ^ sw) * 16) + (hi & 1) * 8) = pk.u;
    }
    __builtin_amdgcn_s_setprio(1);
#pragma unroll
    for (int kk = 0; kk < 4; ++kk) {
      int cb = kk * 4 + hi;
      bf16x8 pf = *(const bf16x8*)(PsW + lr * 256 + ((cb ^ sw) * 16));
#pragma unroll
      for (int nd = 0; nd < 4; ++nd) {
        bf16x8 vf = *(const bf16x8*)&Vs[nd * 16 + lr][(cb ^ sw) * 8];
        ot[nd] = mfma16(vf, pf, ot[nd]);
      }
    }
    __builtin_amdgcn_s_setprio(0);
  };

  auto STORE = [&](f32x4 (&ot)[4], float lrun, int qrow) {
    float rinv = 1.0f / lrun;
    bf16* orow = ob + ((size_t)h * SEQ + qrow) * HD;
#pragma unroll
    for (int nd = 0; nd < 4; ++nd) {
      union { bf16 b[4]; uint2 u; } o;
#pragma unroll
      for (int j = 0; j < 4; ++j) o.b[j] = (bf16)(ot[nd][j] * rinv);
      *(uint2*)(orow + nd * 16 + hi * 4) = o.u;
    }
  };

  STAGE(0);
  for (int t = 0; t < NT; ++t) {
    __syncthreads();                 // stage(t) landed (syncthreads drains vmcnt)
    if (t < ntA) {                   // segment A (block-uniform branch)
      int kv0 = t * 128;
      BODY(kv0, qfA, otA, mA, lA, qrowA, t == ntA - 1);
      if (t == ntA - 1) STORE(otA, lA, qrowA);
    } else {                         // segment B
      int kv0 = (t - ntA) * 128;
      BODY(kv0, qfB, otB, mB, lB, qrowB, t == NT - 1);
    }
    __syncthreads();                 // all reads of Ks/Vs done
    if (t + 1 < NT) {
      int tn = t + 1;
      int kvn = (tn < ntA ? tn : tn - ntA) * 128;
      STAGE(kvn);                    // latency covered by co-resident block
    }
  }
  STORE(otB, lB, qrowB);
}

extern "C" void kernel_launch(void* const* d_in, const int* in_sizes, int n_in,
                              void* d_out, int out_size, void* d_ws, size_t ws_size,
                              hipStream_t stream) {
  const float* hs     = (const float*)d_in[0];
  const float* fc     = (const float*)d_in[1];
  const float* fs     = (const float*)d_in[2];
  // d_in[3] = attention_mask (analytic causal; unused)
  const float* kcache = (const float*)d_in[4];
  const float* vcache = (const float*)d_in[5];
  const float* kmask  = (const float*)d_in[6];
  const float* vmask  = (const float*)d_in[7];
  const float* wq     = (const float*)d_in[8];
  const float* wk     = (const float*)d_in[9];
  const float* wv     = (const float*)d_in[10];
  const float* wo     = (const float*)d_in[11];

  float* y    = (float*)d_out;
  float* kout = y + (size_t)SEQ * DIM;
  float* vout = y + 2 * (size_t)SEQ * DIM;

  char* ws = (char*)d_ws;
  const size_t MB8 = (size_t)SEQ * DIM * sizeof(bf16);  // 8 MiB
  bf16* wqT  = (bf16*)(ws + 0 * MB8);
  bf16* wkT  = (bf16*)(ws + 1 * MB8);
  bf16* wvT  = (bf16*)(ws + 2 * MB8);
  bf16* woT  = (bf16*)(ws + 3 * MB8);
  bf16* hsb  = (bf16*)(ws + 4 * MB8);
  bf16* qraw = (bf16*)(ws + 5 * MB8);
  bf16* kraw = (bf16*)(ws + 6 * MB8);
  bf16* vraw = (bf16*)(ws + 7 * MB8);
  bf16* qb   = (bf16*)(ws + 8 * MB8);
  bf16* kb   = (bf16*)(ws + 9 * MB8);
  bf16* vtb  = (bf16*)(ws + 10 * MB8);
  bf16* ob   = hsb;  // hsb dead after QKV GEMM; reuse for attention output

  prep<<<dim3(32, 32, 5), dim3(256), 0, stream>>>(
      hs, hsb, wq, wk, wv, wo, wqT, wkT, wvT, woT);
  gemm128<bf16><<<dim3(16, 16, 3), dim3(256), 0, stream>>>(
      hsb, wqT, wkT, wvT, qraw, kraw, vraw, SEQ, DIM, DIM);
  qkvprep<<<dim3(SEQ + 1024), dim3(256), 0, stream>>>(
      qraw, kraw, vraw, fc, fs, kcache, kmask, vcache, vmask,
      kout, vout, qb, kb, vtb);
  attn_fwd<<<dim3(256), dim3(512), 0, stream>>>(qb, kb, vtb, ob);
  gemm_out<<<dim3(16, 16), dim3(512), 0, stream>>>(ob, woT, y);
}